// Round 1
// baseline (9512.618 us; speedup 1.0000x reference)
//
#include <hip/hip_runtime.h>
#include <stdint.h>
#include <math.h>

#define T 4096
#define NTAGS 6
#define START_TAG 3
#define STOP_TAG 4
#define NEGV -10000.0f

__device__ __forceinline__ float sigm_fast(float z) {
  return 1.f / (1.f + __expf(-z));
}
__device__ __forceinline__ float tanh_fast(float z) {
  return 1.f - 2.f / (1.f + __expf(2.f * z));   // exact at +/-inf saturation
}

typedef _Float16 half2v __attribute__((ext_vector_type(2)));
__device__ __forceinline__ float dot2acc(unsigned a, unsigned b, float c) {
  return __builtin_amdgcn_fdot2(__builtin_bit_cast(half2v, a),
                                __builtin_bit_cast(half2v, b), c, false);
}
__device__ __forceinline__ unsigned short f16b(float x) {
  _Float16 h = (_Float16)x;
  return __builtin_bit_cast(unsigned short, h);
}

// ---------------------------------------------------------------------------
// K0: transpose w_ih (both dirs) into wT[k][col], NEW cell-major col order:
// col = d*1024 + cell*4 + gate. Combined bias in same order.
// ---------------------------------------------------------------------------
__global__ __launch_bounds__(256) void k0_prep(
    const float* __restrict__ wf, const float* __restrict__ wb,
    const float* __restrict__ bif, const float* __restrict__ bhf,
    const float* __restrict__ bib, const float* __restrict__ bhb,
    float* __restrict__ wT, float* __restrict__ bias2) {
  int idx = blockIdx.x * 256 + threadIdx.x;   // 0 .. 524287
  int k = idx >> 11, col = idx & 2047;
  int d = col >> 10, low = col & 1023;
  int cc = low >> 2, g = low & 3;
  int grow = g * 256 + cc;                    // row in original w_ih
  const float* w = d ? wb : wf;
  wT[idx] = w[grow * 256 + k];                // wT[k*2048 + col]
  if (idx < 2048)
    bias2[idx] = d ? (bib[grow] + bhb[grow]) : (bif[grow] + bhf[grow]);
}

// ---------------------------------------------------------------------------
// K1: zpre[d][t][cell*4+g] = emb[sent[t]] . w_ih[d][g*256+cell] + b_ih + b_hh
// (cell-major layout so k2 waves read one fully-used 64B line per step)
// ---------------------------------------------------------------------------
__global__ __launch_bounds__(256) void k1_zpre(
    const int* __restrict__ sent, const float* __restrict__ emb,
    const float* __restrict__ wT, const float* __restrict__ bias2,
    float* __restrict__ zpre) {
  int tb = blockIdx.x, cb = blockIdx.y;
  int tid = threadIdx.x;
  int col = cb * 256 + tid;                   // NEW order col
  int d = col >> 10, low = col & 1023;
  __shared__ float xs[32 * 256];
  int t0 = tb * 32;
  for (int r = 0; r < 32; r++) {
    int s = sent[t0 + r];                       // uniform -> scalar broadcast
    xs[r * 256 + tid] = emb[(size_t)s * 256 + tid];
  }
  __syncthreads();
  float acc[32];
#pragma unroll
  for (int r = 0; r < 32; r++) acc[r] = 0.f;
  const float4* xs4 = (const float4*)xs;
  for (int kq = 0; kq < 64; kq++) {
    float w0 = wT[(4 * kq + 0) * 2048 + col];
    float w1 = wT[(4 * kq + 1) * 2048 + col];
    float w2 = wT[(4 * kq + 2) * 2048 + col];
    float w3 = wT[(4 * kq + 3) * 2048 + col];
#pragma unroll
    for (int r = 0; r < 32; r++) {
      float4 x4 = xs4[r * 64 + kq];             // uniform address -> broadcast
      acc[r] += w0 * x4.x + w1 * x4.y + w2 * x4.z + w3 * x4.w;
    }
  }
  float bb = bias2[col];
  for (int r = 0; r < 32; r++)
    zpre[((size_t)d * T + (t0 + r)) * 1024 + low] = acc[r] + bb;
}

// ---------------------------------------------------------------------------
// K2 v5: wave-autonomous row-split. 32 WGs (d*16+sub), 256 thr = 4 waves.
// Wave owns 4 cells end-to-end. Lane = (cell j, gate g, kslice s):
//   l = j*16 + g*4 + s ; row = g*256+cell ; k in [64s, 64s+64).
// Weights VGPR-resident (32 packed-f16 dwords/lane). k-reduce = shfl_xor
// butterfly; gate gather = 4 shfl; activations replicated across 16 lanes.
// NO __syncthreads in the step loop; h exchange via the tagged agent-scope
// ring (depth-2 parity, identical protocol). Per-wave LDS: padded h buffer
// hq[4][36] dwords -> conflict-free b128 broadcast reads.
// ---------------------------------------------------------------------------
__global__ __launch_bounds__(256) void k2_lstm(
    const float* __restrict__ zpre,
    const float* __restrict__ whf, const float* __restrict__ whb,
    const float* __restrict__ h0, const float* __restrict__ c0,
    float* h_all, unsigned long long* ring) {
  int w = blockIdx.x;
  int d = w >> 4, sub = w & 15;
  const float* w_hh = d ? whb : whf;
  int tid = threadIdx.x;
  int q = tid >> 6, l = tid & 63;
  int j = l >> 4, g = (l >> 2) & 3, s = l & 3;
  int cell = sub * 16 + q * 4 + j;              // cell index within direction
  int row = g * 256 + cell;                     // w_hh row

  __shared__ __align__(16) unsigned hq[4][4][36];  // [wave][sblk][32+pad]

  // ---- stage this lane's weights into VGPRs: k in [s*64, s*64+64) ----
  unsigned wreg[32];
  {
    const float4* wp = (const float4*)(w_hh + (size_t)row * 256 + s * 64);
#pragma unroll
    for (int m = 0; m < 16; m++) {
      float4 v = wp[m];
      wreg[2 * m]     = (unsigned)f16b(v.x) | ((unsigned)f16b(v.y) << 16);
      wreg[2 * m + 1] = (unsigned)f16b(v.z) | ((unsigned)f16b(v.w) << 16);
    }
  }
  // ---- h0 into hq: lane fills entries 2l,2l+1 = h elems 4l..4l+3 ----
  {
    float4 h4 = *(const float4*)(h0 + d * 256 + 4 * l);
    unsigned e0 = (unsigned)f16b(h4.x) | ((unsigned)f16b(h4.y) << 16);
    unsigned e1 = (unsigned)f16b(h4.z) | ((unsigned)f16b(h4.w) << 16);
    *(unsigned long long*)&hq[q][l >> 4][(2 * l) & 31] =
        ((unsigned long long)e1 << 32) | e0;
  }

  float c = c0[d * 256 + cell];
  const float* zp_d = zpre + (size_t)d * T * 1024;
  float* h_d = h_all + (size_t)d * T * 256;
  unsigned long long* rg = ring + (size_t)d * 2 * 128;
  int zoff = sub * 64 + (q * 4 + j) * 4 + g;    // cell-major zpre offset

  int t0 = d ? (T - 1) : 0;
  float zv = zp_d[(size_t)t0 * 1024 + zoff];

  for (int st = 0; st < T; st++) {
    int t = d ? (T - 1 - st) : st;
    // prefetch next-step zpre: latency hides under this whole iteration
    float zn = 0.f;
    if (st + 1 < T) {
      int tn = d ? (t - 1) : (t + 1);
      zn = zp_d[(size_t)tn * 1024 + zoff];
    }
    if (st > 0) {
      unsigned exp_tag = (unsigned)st;          // tag of step st-1 is st
      unsigned long long* a0 = &rg[((st - 1) & 1) * 128 + 2 * l];
      // prime both loads so the common case costs one MALL round-trip
      unsigned long long v0 =
          __hip_atomic_load(a0, __ATOMIC_RELAXED, __HIP_MEMORY_SCOPE_AGENT);
      unsigned long long v1 =
          __hip_atomic_load(a0 + 1, __ATOMIC_RELAXED, __HIP_MEMORY_SCOPE_AGENT);
      while ((unsigned)(v0 >> 32) != exp_tag)
        v0 = __hip_atomic_load(a0, __ATOMIC_RELAXED, __HIP_MEMORY_SCOPE_AGENT);
      while ((unsigned)(v1 >> 32) != exp_tag)
        v1 = __hip_atomic_load(a0 + 1, __ATOMIC_RELAXED,
                               __HIP_MEMORY_SCOPE_AGENT);
      *(unsigned long long*)&hq[q][l >> 4][(2 * l) & 31] =
          (v1 << 32) | (unsigned)v0;            // two packed h2 dwords
    }
    __builtin_amdgcn_wave_barrier();            // order hq writes vs reads

    const uint4* hp = (const uint4*)&hq[q][s][0];  // wave-broadcast reads
    float acc = 0.f;
#pragma unroll
    for (int m = 0; m < 8; m++) {
      uint4 h4 = hp[m];
      acc = dot2acc(wreg[4 * m + 0], h4.x, acc);
      acc = dot2acc(wreg[4 * m + 1], h4.y, acc);
      acc = dot2acc(wreg[4 * m + 2], h4.z, acc);
      acc = dot2acc(wreg[4 * m + 3], h4.w, acc);
    }
    // k-reduce over the 4 slices (commutative pairing -> identical in all
    // replica lanes)
    acc += __shfl_xor(acc, 1);
    acc += __shfl_xor(acc, 2);
    float z = acc + zv;
    float a = (g == 2) ? tanh_fast(z) : sigm_fast(z);
    int base = l & 0x33;                        // (j, g=0, s)
    float ai = __shfl(a, base);
    float af = __shfl(a, base | 4);
    float ag = __shfl(a, base | 8);
    float ao = __shfl(a, base | 12);
    c = af * c + ai * ag;                       // all 16 replicas identical
    float hvl = ao * tanh_fast(c);
    float hnx = __shfl(hvl, l + 16);            // h of cell j+1 (for j even)

    if ((l & 15) == 0)                          // g==0, s==0: 4 lanes/wave
      h_d[(size_t)t * 256 + cell] = hvl;        // fp32 history for k3
    if ((l & 31) == 0) {                        // j even: pack 2 h per entry
      unsigned h2 = (unsigned)f16b(hvl) | ((unsigned)f16b(hnx) << 16);
      __hip_atomic_store(&rg[(st & 1) * 128 + sub * 8 + q * 2 + (j >> 1)],
                         ((unsigned long long)(unsigned)(st + 1) << 32) | h2,
                         __ATOMIC_RELAXED, __HIP_MEMORY_SCOPE_AGENT);
    }
    zv = zn;
  }
}

// ---------------------------------------------------------------------------
// K3: feats[t][tag] = [hf[t]; hb[t]] . W_out[tag] + b_out[tag]
// ---------------------------------------------------------------------------
__global__ __launch_bounds__(64) void k3_feats(
    const float* __restrict__ h_all, const float* __restrict__ Wout,
    const float* __restrict__ bout, float* __restrict__ feats) {
  int t = blockIdx.x;
  int j = threadIdx.x;
  const float* hf = h_all + (size_t)t * 256;
  const float* hb = h_all + (size_t)T * 256 + (size_t)t * 256;
  float s[6];
#pragma unroll
  for (int g = 0; g < 6; g++) s[g] = 0.f;
#pragma unroll
  for (int m = 0; m < 4; m++) {
    float a = hf[j + 64 * m];
#pragma unroll
    for (int g = 0; g < 6; g++) s[g] += a * Wout[g * 512 + j + 64 * m];
  }
#pragma unroll
  for (int m = 0; m < 4; m++) {
    float b = hb[j + 64 * m];
#pragma unroll
    for (int g = 0; g < 6; g++) s[g] += b * Wout[g * 512 + 256 + j + 64 * m];
  }
#pragma unroll
  for (int g = 0; g < 6; g++) {
#pragma unroll
    for (int off = 32; off >= 1; off >>= 1) s[g] += __shfl_xor(s[g], off);
  }
  if (j < 6) feats[(size_t)t * 6 + j] = s[j] + bout[j];
}

// ---------------------------------------------------------------------------
// K4: Viterbi forward (serial, first-max argmax like jnp.argmax) + parallel
// backtrace via 6-entry map-composition suffix scan. Single wave.
// ---------------------------------------------------------------------------
__global__ __launch_bounds__(64) void k4_viterbi(
    const float* __restrict__ feats, const float* __restrict__ trans,
    float* __restrict__ out) {
  __shared__ unsigned char bp_lds[T * 8];
  __shared__ float fbuf[2][64 * 6];
  int lane = threadIdx.x;

  float tr[6];
#pragma unroll
  for (int f = 0; f < 6; f++) tr[f] = (lane < 6) ? trans[lane * 6 + f] : 0.f;
  float fv = (lane == START_TAG) ? 0.f : NEGV;

  for (int idx = lane; idx < 384; idx += 64) fbuf[0][idx] = feats[idx];

  for (int cch = 0; cch < 64; cch++) {
    float pf[6];
    if (cch + 1 < 64) {
#pragma unroll
      for (int m = 0; m < 6; m++)
        pf[m] = feats[(cch + 1) * 384 + lane + 64 * m];   // prefetch in regs
    }
    const float* fb = fbuf[cch & 1];
    for (int j = 0; j < 64; j++) {
      int t = cch * 64 + j;
      float best = -3.4e38f;
      int bi = 0;
#pragma unroll
      for (int f = 0; f < 6; f++) {
        float v = __shfl(fv, f) + tr[f];     // trans[to][from] + fv[from]
        if (v > best) { best = v; bi = f; }  // strict > => first max index
      }
      float nfv = best + fb[j * 6 + (lane < 6 ? lane : 0)];
      if (lane < 6) {
        fv = nfv;
        bp_lds[t * 8 + lane] = (unsigned char)bi;
      }
    }
    if (cch + 1 < 64) {
#pragma unroll
      for (int m = 0; m < 6; m++)
        fbuf[(cch + 1) & 1][lane + 64 * m] = pf[m];
    }
  }

  float term = (lane < 6) ? (fv + trans[STOP_TAG * 6 + lane]) : -3.4e38f;
  float bestv = -3.4e38f;
  int bestt = 0;
#pragma unroll
  for (int f = 0; f < 6; f++) {
    float v = __shfl(term, f);
    if (v > bestv) { bestv = v; bestt = f; }
  }
  if (lane == 0) out[0] = bestv;

  // backtrace: path[t] = S_t(best), S_t = M_{t+1} o ... o M_{T-1}
  unsigned int ident = 0;
#pragma unroll
  for (int i = 0; i < 6; i++) ident |= (unsigned)i << (3 * i);

  unsigned int p = ident;                 // P_L = M_{64L} o ... o M_{64L+63}
  int base = lane * 64;
  for (int j2 = 0; j2 < 64; j2++) {
    const unsigned int* bw = (const unsigned int*)&bp_lds[(base + j2) * 8];
    unsigned int lo = bw[0], hi = bw[1];
    unsigned int mw = (lo & 7) | (((lo >> 8) & 7) << 3) | (((lo >> 16) & 7) << 6)
                    | (((lo >> 24) & 7) << 9) | ((hi & 7) << 12)
                    | (((hi >> 8) & 7) << 15);
    unsigned int np = 0;
#pragma unroll
    for (int i = 0; i < 6; i++) {
      unsigned int b = (mw >> (3 * i)) & 7;
      np |= ((p >> (3 * b)) & 7) << (3 * i);   // p := p o M_t
    }
    p = np;
  }
  unsigned int suf = p;   // suffix scan: suf_L = P_L o ... o P_63
#pragma unroll
  for (int off = 1; off < 64; off <<= 1) {
    unsigned int other = __shfl_down(suf, off);
    if (lane + off < 64) {
      unsigned int ns = 0;
#pragma unroll
      for (int i = 0; i < 6; i++) {
        unsigned int b = (other >> (3 * i)) & 7;
        ns |= ((suf >> (3 * b)) & 7) << (3 * i);   // suf := suf o other
      }
      suf = ns;
    }
  }
  unsigned int tail = __shfl_down(suf, 1);     // Suf_{L+1}
  if (lane == 63) tail = ident;
  unsigned int cur = tail;                     // = S_{64L+63}
  for (int j2 = 63; j2 >= 0; j2--) {
    int t = base + j2;
    out[1 + t] = (float)((cur >> (3 * bestt)) & 7);
    const unsigned int* bw = (const unsigned int*)&bp_lds[t * 8];
    unsigned int lo = bw[0], hi = bw[1];
    unsigned int mw = (lo & 7) | (((lo >> 8) & 7) << 3) | (((lo >> 16) & 7) << 6)
                    | (((lo >> 24) & 7) << 9) | ((hi & 7) << 12)
                    | (((hi >> 8) & 7) << 15);
    unsigned int nc = 0;
#pragma unroll
    for (int i = 0; i < 6; i++) {
      unsigned int b = (cur >> (3 * i)) & 7;
      nc |= ((mw >> (3 * b)) & 7) << (3 * i);  // cur := M_t o cur
    }
    cur = nc;
  }
}

// ---------------------------------------------------------------------------
extern "C" void kernel_launch(void* const* d_in, const int* in_sizes, int n_in,
                              void* d_out, int out_size, void* d_ws, size_t ws_size,
                              hipStream_t stream) {
  const int*   sent  = (const int*)d_in[0];
  const float* emb   = (const float*)d_in[1];
  const float* wihf  = (const float*)d_in[2];
  const float* whhf  = (const float*)d_in[3];
  const float* bihf  = (const float*)d_in[4];
  const float* bhhf  = (const float*)d_in[5];
  const float* wihb  = (const float*)d_in[6];
  const float* whhb  = (const float*)d_in[7];
  const float* bihb  = (const float*)d_in[8];
  const float* bhhb  = (const float*)d_in[9];
  const float* Wout  = (const float*)d_in[10];
  const float* bout  = (const float*)d_in[11];
  const float* trans = (const float*)d_in[12];
  const float* h0    = (const float*)d_in[13];
  const float* c0    = (const float*)d_in[14];
  float* out = (float*)d_out;

  char* ws = (char*)d_ws;
  float*              zpre  = (float*)(ws + 0);          // 32 MiB
  float*              h_all = (float*)(ws + 33554432);   //  8 MiB
  float*              wT    = (float*)(ws + 41943040);   //  2 MiB
  float*              bias2 = (float*)(ws + 44040192);   //  8 KiB
  float*              feats = (float*)(ws + 44048384);   // 96 KiB
  unsigned long long* ring  = (unsigned long long*)(ws + 44146688); // 4 KiB

  k0_prep<<<2048, 256, 0, stream>>>(wihf, wihb, bihf, bhhf, bihb, bhhb, wT, bias2);
  dim3 g1(128, 8);
  k1_zpre<<<g1, 256, 0, stream>>>(sent, emb, wT, bias2, zpre);
  k2_lstm<<<32, 256, 0, stream>>>(zpre, whhf, whhb, h0, c0, h_all, ring);
  k3_feats<<<4096, 64, 0, stream>>>(h_all, Wout, bout, feats);
  k4_viterbi<<<1, 64, 0, stream>>>(feats, trans, out);
}

// Round 2
// 6654.231 us; speedup vs baseline: 1.4296x; 1.4296x over previous
//
#include <hip/hip_runtime.h>
#include <stdint.h>
#include <math.h>

#define T 4096
#define NTAGS 6
#define START_TAG 3
#define STOP_TAG 4
#define NEGV -10000.0f

__device__ __forceinline__ float sigm_fast(float z) {
  return 1.f / (1.f + __expf(-z));
}
__device__ __forceinline__ float tanh_fast(float z) {
  return 1.f - 2.f / (1.f + __expf(2.f * z));   // exact at +/-inf saturation
}

typedef _Float16 half2v __attribute__((ext_vector_type(2)));
__device__ __forceinline__ float dot2acc(unsigned a, unsigned b, float c) {
  return __builtin_amdgcn_fdot2(__builtin_bit_cast(half2v, a),
                                __builtin_bit_cast(half2v, b), c, false);
}
__device__ __forceinline__ unsigned short f16b(float x) {
  _Float16 h = (_Float16)x;
  return __builtin_bit_cast(unsigned short, h);
}
__device__ __forceinline__ unsigned pack2(float a, float b) {
  return (unsigned)f16b(a) | ((unsigned)f16b(b) << 16);
}

// ---------------------------------------------------------------------------
// K0: transpose w_ih (both dirs) into wT[k][col], col = d*1024+g (gate-major);
// combined bias. (identical to the 6459us baseline)
// ---------------------------------------------------------------------------
__global__ __launch_bounds__(256) void k0_prep(
    const float* __restrict__ wf, const float* __restrict__ wb,
    const float* __restrict__ bif, const float* __restrict__ bhf,
    const float* __restrict__ bib, const float* __restrict__ bhb,
    float* __restrict__ wT, float* __restrict__ bias2) {
  int idx = blockIdx.x * 256 + threadIdx.x;   // 0 .. 524287
  int k = idx >> 11, col = idx & 2047;
  int d = col >> 10, g = col & 1023;
  const float* w = d ? wb : wf;
  wT[idx] = w[g * 256 + k];                   // wT[k*2048 + col]
  if (idx < 2048) bias2[idx] = d ? (bib[g] + bhb[g]) : (bif[g] + bhf[g]);
}

// ---------------------------------------------------------------------------
// K1: zpre[d][t][g] = emb[sent[t]] . w_ih[d][g] + b_ih + b_hh   (gate-major)
// ---------------------------------------------------------------------------
__global__ __launch_bounds__(256) void k1_zpre(
    const int* __restrict__ sent, const float* __restrict__ emb,
    const float* __restrict__ wT, const float* __restrict__ bias2,
    float* __restrict__ zpre) {
  int tb = blockIdx.x, cb = blockIdx.y;
  int tid = threadIdx.x;
  int col = cb * 256 + tid;
  int d = col >> 10, g = col & 1023;
  __shared__ float xs[32 * 256];
  int t0 = tb * 32;
  for (int r = 0; r < 32; r++) {
    int s = sent[t0 + r];                       // uniform -> scalar broadcast
    xs[r * 256 + tid] = emb[(size_t)s * 256 + tid];
  }
  __syncthreads();
  float acc[32];
#pragma unroll
  for (int r = 0; r < 32; r++) acc[r] = 0.f;
  const float4* xs4 = (const float4*)xs;
  for (int kq = 0; kq < 64; kq++) {
    float w0 = wT[(4 * kq + 0) * 2048 + col];
    float w1 = wT[(4 * kq + 1) * 2048 + col];
    float w2 = wT[(4 * kq + 2) * 2048 + col];
    float w3 = wT[(4 * kq + 3) * 2048 + col];
#pragma unroll
    for (int r = 0; r < 32; r++) {
      float4 x4 = xs4[r * 64 + kq];             // uniform address -> broadcast
      acc[r] += w0 * x4.x + w1 * x4.y + w2 * x4.z + w3 * x4.w;
    }
  }
  float bb = bias2[col];
  for (int r = 0; r < 32; r++)
    zpre[((size_t)d * T + (t0 + r)) * 1024 + g] = acc[r] + bb;
}

// ---------------------------------------------------------------------------
// K2 v6: v4's k-split poll pattern + v5's barrier-free body.
// 32 WGs (d*16+sub), 256 thr = 4 waves. Wave q: all 64 gate-rows of the WG,
// k in [64q, 64q+64). Lane l = row (gate=l>>4, cell=l&15); weights in VGPRs
// (32 packed-f16 dwords). Wave polls ONLY its 32 ring entries (v4 volume).
// Cross-wave z-reduction: parity-double-buffered LDS partials + per-wave
// release/acquire tags -> NO __syncthreads in the step loop, so the
// agent-scope ring store is never drained by a barrier.
// z summation order bitwise-identical to v4: zs[0]+zs[1]+zs[2]+zs[3]+zv.
// ---------------------------------------------------------------------------
__global__ __launch_bounds__(256) void k2_lstm(
    const float* __restrict__ zpre,
    const float* __restrict__ whf, const float* __restrict__ whb,
    const float* __restrict__ h0, const float* __restrict__ c0,
    float* h_all, unsigned long long* ring) {
  int w = blockIdx.x;
  int d = w >> 4, sub = w & 15;
  const float* w_hh = d ? whb : whf;
  int tid = threadIdx.x;
  int q = tid >> 6, l = tid & 63;
  int gate = l >> 4, cell = l & 15;
  int row = gate * 256 + sub * 16 + cell;       // w_hh row owned by this lane

  __shared__ __align__(16) unsigned hq[4][36];  // per-wave h k-slice (64 f16)
  __shared__ float zs[2][4][64];                // [parity][wave][row] partials
  __shared__ int tg[2][4];                      // [parity][wave] step tags

  // ---- stage this lane's weight k-slice into VGPRs: k in [q*64, q*64+64) --
  unsigned wreg[32];
  {
    const float4* wp = (const float4*)(w_hh + (size_t)row * 256 + q * 64);
#pragma unroll
    for (int m = 0; m < 8; m++) {
      float4 v0 = wp[2 * m], v1 = wp[2 * m + 1];
      wreg[4 * m + 0] = pack2(v0.x, v0.y);
      wreg[4 * m + 1] = pack2(v0.z, v0.w);
      wreg[4 * m + 2] = pack2(v1.x, v1.y);
      wreg[4 * m + 3] = pack2(v1.z, v1.w);
    }
  }
  // ---- h0 k-slice into hq (same packing as ring entries) ----
  if (l < 32)
    hq[q][l] = pack2(h0[d * 256 + q * 64 + 2 * l],
                     h0[d * 256 + q * 64 + 2 * l + 1]);
  float c = c0[d * 256 + sub * 16 + cell];

  if (tid < 8) ((int*)tg)[tid] = 0;             // LDS tags must start clean
  __syncthreads();                              // once, before the step loop

  const float* zp_d = zpre + (size_t)d * T * 1024;
  float* h_d = h_all + (size_t)d * T * 256;
  unsigned long long* rg = ring + (size_t)d * 2 * 128;
  int zoff = gate * 256 + sub * 16 + cell;      // gate-major zpre offset

  int t0 = d ? (T - 1) : 0;
  float zv = zp_d[(size_t)t0 * 1024 + zoff];

  for (int st = 0; st < T; st++) {
    int t = d ? (T - 1 - st) : st;
    // prefetch next-step zpre BEFORE the poll: HBM latency hides under spin
    float zn = 0.f;
    if (st + 1 < T) {
      int tn = d ? (t - 1) : (t + 1);
      zn = zp_d[(size_t)tn * 1024 + zoff];
    }
    if (st > 0) {
      if (l < 32) {                             // v4's exact poll pattern
        unsigned exp_tag = (unsigned)st;        // tag of step st-1 is st
        unsigned long long* addr = &rg[((st - 1) & 1) * 128 + q * 32 + l];
        unsigned long long v;
        do {
          v = __hip_atomic_load(addr, __ATOMIC_RELAXED,
                                __HIP_MEMORY_SCOPE_AGENT);
        } while ((unsigned)(v >> 32) != exp_tag);
        hq[q][l] = (unsigned)v;                 // wave-private slice
      }
      __builtin_amdgcn_wave_barrier();          // order hq write vs reads
    }

    const uint4* hv = (const uint4*)hq[q];
    float acc = 0.f;
#pragma unroll
    for (int m = 0; m < 8; m++) {
      uint4 h4 = hv[m];                         // wave-uniform broadcast
      acc = dot2acc(wreg[4 * m + 0], h4.x, acc);
      acc = dot2acc(wreg[4 * m + 1], h4.y, acc);
      acc = dot2acc(wreg[4 * m + 2], h4.z, acc);
      acc = dot2acc(wreg[4 * m + 3], h4.w, acc);
    }
    int p = st & 1;
    zs[p][q][l] = acc;                          // conflict-free (stride-1)
    if (l == 0)                                 // release: drains wave's LDS
      __hip_atomic_store(&tg[p][q], st + 1, __ATOMIC_RELEASE,
                         __HIP_MEMORY_SCOPE_WORKGROUP);
    // spin until all four waves posted this step's partials (~1 LDS RT)
    for (;;) {
      int a0 = __hip_atomic_load(&tg[p][0], __ATOMIC_ACQUIRE,
                                 __HIP_MEMORY_SCOPE_WORKGROUP);
      int a1 = __hip_atomic_load(&tg[p][1], __ATOMIC_ACQUIRE,
                                 __HIP_MEMORY_SCOPE_WORKGROUP);
      int a2 = __hip_atomic_load(&tg[p][2], __ATOMIC_ACQUIRE,
                                 __HIP_MEMORY_SCOPE_WORKGROUP);
      int a3 = __hip_atomic_load(&tg[p][3], __ATOMIC_ACQUIRE,
                                 __HIP_MEMORY_SCOPE_WORKGROUP);
      if (a0 == st + 1 && a1 == st + 1 && a2 == st + 1 && a3 == st + 1) break;
    }
    // v4-identical FP order: zs[0]+zs[1]+zs[2]+zs[3]+zv
    float z = zs[p][0][l] + zs[p][1][l] + zs[p][2][l] + zs[p][3][l] + zv;
    float a = (gate == 2) ? tanh_fast(z) : sigm_fast(z);
    float ai = __shfl(a, cell);                 // gate 0 lane for this cell
    float af = __shfl(a, 16 + cell);
    float ag = __shfl(a, 32 + cell);
    float ao = __shfl(a, 48 + cell);
    c = af * c + ai * ag;                       // replicated across 4 gates
    float hvl = ao * tanh_fast(c);
    if (q == 0) {                               // wave 0 publishes h
      float hnx = __shfl(hvl, l + 1);           // h of cell+1 (for even l)
      if (l < 16) {
        h_d[(size_t)t * 256 + sub * 16 + l] = hvl;  // fp32 history for k3
        if ((l & 1) == 0) {                     // pack 2 h per tagged entry
          unsigned h2 = pack2(0.f, 0.f);
          h2 = (unsigned)f16b(hvl) | ((unsigned)f16b(hnx) << 16);
          __hip_atomic_store(&rg[p * 128 + sub * 8 + (l >> 1)],
                             ((unsigned long long)(unsigned)(st + 1) << 32) | h2,
                             __ATOMIC_RELAXED, __HIP_MEMORY_SCOPE_AGENT);
        }
      }
    }
    zv = zn;
  }
}

// ---------------------------------------------------------------------------
// K3: feats[t][tag] = [hf[t]; hb[t]] . W_out[tag] + b_out[tag]
// ---------------------------------------------------------------------------
__global__ __launch_bounds__(64) void k3_feats(
    const float* __restrict__ h_all, const float* __restrict__ Wout,
    const float* __restrict__ bout, float* __restrict__ feats) {
  int t = blockIdx.x;
  int j = threadIdx.x;
  const float* hf = h_all + (size_t)t * 256;
  const float* hb = h_all + (size_t)T * 256 + (size_t)t * 256;
  float s[6];
#pragma unroll
  for (int g = 0; g < 6; g++) s[g] = 0.f;
#pragma unroll
  for (int m = 0; m < 4; m++) {
    float a = hf[j + 64 * m];
#pragma unroll
    for (int g = 0; g < 6; g++) s[g] += a * Wout[g * 512 + j + 64 * m];
  }
#pragma unroll
  for (int m = 0; m < 4; m++) {
    float b = hb[j + 64 * m];
#pragma unroll
    for (int g = 0; g < 6; g++) s[g] += b * Wout[g * 512 + 256 + j + 64 * m];
  }
#pragma unroll
  for (int g = 0; g < 6; g++) {
#pragma unroll
    for (int off = 32; off >= 1; off >>= 1) s[g] += __shfl_xor(s[g], off);
  }
  if (j < 6) feats[(size_t)t * 6 + j] = s[j] + bout[j];
}

// ---------------------------------------------------------------------------
// K4: Viterbi forward (serial, first-max argmax like jnp.argmax) + parallel
// backtrace via 6-entry map-composition suffix scan. Single wave.
// ---------------------------------------------------------------------------
__global__ __launch_bounds__(64) void k4_viterbi(
    const float* __restrict__ feats, const float* __restrict__ trans,
    float* __restrict__ out) {
  __shared__ unsigned char bp_lds[T * 8];
  __shared__ float fbuf[2][64 * 6];
  int lane = threadIdx.x;

  float tr[6];
#pragma unroll
  for (int f = 0; f < 6; f++) tr[f] = (lane < 6) ? trans[lane * 6 + f] : 0.f;
  float fv = (lane == START_TAG) ? 0.f : NEGV;

  for (int idx = lane; idx < 384; idx += 64) fbuf[0][idx] = feats[idx];

  for (int cch = 0; cch < 64; cch++) {
    float pf[6];
    if (cch + 1 < 64) {
#pragma unroll
      for (int m = 0; m < 6; m++)
        pf[m] = feats[(cch + 1) * 384 + lane + 64 * m];   // prefetch in regs
    }
    const float* fb = fbuf[cch & 1];
    for (int j = 0; j < 64; j++) {
      int t = cch * 64 + j;
      float best = -3.4e38f;
      int bi = 0;
#pragma unroll
      for (int f = 0; f < 6; f++) {
        float v = __shfl(fv, f) + tr[f];     // trans[to][from] + fv[from]
        if (v > best) { best = v; bi = f; }  // strict > => first max index
      }
      float nfv = best + fb[j * 6 + (lane < 6 ? lane : 0)];
      if (lane < 6) {
        fv = nfv;
        bp_lds[t * 8 + lane] = (unsigned char)bi;
      }
    }
    if (cch + 1 < 64) {
#pragma unroll
      for (int m = 0; m < 6; m++)
        fbuf[(cch + 1) & 1][lane + 64 * m] = pf[m];
    }
  }

  float term = (lane < 6) ? (fv + trans[STOP_TAG * 6 + lane]) : -3.4e38f;
  float bestv = -3.4e38f;
  int bestt = 0;
#pragma unroll
  for (int f = 0; f < 6; f++) {
    float v = __shfl(term, f);
    if (v > bestv) { bestv = v; bestt = f; }
  }
  if (lane == 0) out[0] = bestv;

  // backtrace: path[t] = S_t(best), S_t = M_{t+1} o ... o M_{T-1}
  unsigned int ident = 0;
#pragma unroll
  for (int i = 0; i < 6; i++) ident |= (unsigned)i << (3 * i);

  unsigned int p = ident;                 // P_L = M_{64L} o ... o M_{64L+63}
  int base = lane * 64;
  for (int j2 = 0; j2 < 64; j2++) {
    const unsigned int* bw = (const unsigned int*)&bp_lds[(base + j2) * 8];
    unsigned int lo = bw[0], hi = bw[1];
    unsigned int mw = (lo & 7) | (((lo >> 8) & 7) << 3) | (((lo >> 16) & 7) << 6)
                    | (((lo >> 24) & 7) << 9) | ((hi & 7) << 12)
                    | (((hi >> 8) & 7) << 15);
    unsigned int np = 0;
#pragma unroll
    for (int i = 0; i < 6; i++) {
      unsigned int b = (mw >> (3 * i)) & 7;
      np |= ((p >> (3 * b)) & 7) << (3 * i);   // p := p o M_t
    }
    p = np;
  }
  unsigned int suf = p;   // suffix scan: suf_L = P_L o ... o P_63
#pragma unroll
  for (int off = 1; off < 64; off <<= 1) {
    unsigned int other = __shfl_down(suf, off);
    if (lane + off < 64) {
      unsigned int ns = 0;
#pragma unroll
      for (int i = 0; i < 6; i++) {
        unsigned int b = (other >> (3 * i)) & 7;
        ns |= ((suf >> (3 * b)) & 7) << (3 * i);   // suf := suf o other
      }
      suf = ns;
    }
  }
  unsigned int tail = __shfl_down(suf, 1);     // Suf_{L+1}
  if (lane == 63) tail = ident;
  unsigned int cur = tail;                     // = S_{64L+63}
  for (int j2 = 63; j2 >= 0; j2--) {
    int t = base + j2;
    out[1 + t] = (float)((cur >> (3 * bestt)) & 7);
    const unsigned int* bw = (const unsigned int*)&bp_lds[t * 8];
    unsigned int lo = bw[0], hi = bw[1];
    unsigned int mw = (lo & 7) | (((lo >> 8) & 7) << 3) | (((lo >> 16) & 7) << 6)
                    | (((lo >> 24) & 7) << 9) | ((hi & 7) << 12)
                    | (((hi >> 8) & 7) << 15);
    unsigned int nc = 0;
#pragma unroll
    for (int i = 0; i < 6; i++) {
      unsigned int b = (cur >> (3 * i)) & 7;
      nc |= ((mw >> (3 * b)) & 7) << (3 * i);  // cur := M_t o cur
    }
    cur = nc;
  }
}

// ---------------------------------------------------------------------------
extern "C" void kernel_launch(void* const* d_in, const int* in_sizes, int n_in,
                              void* d_out, int out_size, void* d_ws, size_t ws_size,
                              hipStream_t stream) {
  const int*   sent  = (const int*)d_in[0];
  const float* emb   = (const float*)d_in[1];
  const float* wihf  = (const float*)d_in[2];
  const float* whhf  = (const float*)d_in[3];
  const float* bihf  = (const float*)d_in[4];
  const float* bhhf  = (const float*)d_in[5];
  const float* wihb  = (const float*)d_in[6];
  const float* whhb  = (const float*)d_in[7];
  const float* bihb  = (const float*)d_in[8];
  const float* bhhb  = (const float*)d_in[9];
  const float* Wout  = (const float*)d_in[10];
  const float* bout  = (const float*)d_in[11];
  const float* trans = (const float*)d_in[12];
  const float* h0    = (const float*)d_in[13];
  const float* c0    = (const float*)d_in[14];
  float* out = (float*)d_out;

  char* ws = (char*)d_ws;
  float*              zpre  = (float*)(ws + 0);          // 32 MiB
  float*              h_all = (float*)(ws + 33554432);   //  8 MiB
  float*              wT    = (float*)(ws + 41943040);   //  2 MiB
  float*              bias2 = (float*)(ws + 44040192);   //  8 KiB
  float*              feats = (float*)(ws + 44048384);   // 96 KiB
  unsigned long long* ring  = (unsigned long long*)(ws + 44146688); // 4 KiB

  k0_prep<<<2048, 256, 0, stream>>>(wihf, wihb, bihf, bhhf, bihb, bhhb, wT, bias2);
  dim3 g1(128, 8);
  k1_zpre<<<g1, 256, 0, stream>>>(sent, emb, wT, bias2, zpre);
  k2_lstm<<<32, 256, 0, stream>>>(zpre, whhf, whhb, h0, c0, h_all, ring);
  k3_feats<<<4096, 64, 0, stream>>>(h_all, Wout, bout, feats);
  k4_viterbi<<<1, 64, 0, stream>>>(feats, trans, out);
}